// Round 1
// baseline (256.259 us; speedup 1.0000x reference)
//
#include <hip/hip_runtime.h>
#include <hip/hip_bf16.h>

typedef __attribute__((ext_vector_type(8))) short bfrag;
typedef __attribute__((ext_vector_type(4))) float facc;
typedef __attribute__((ext_vector_type(4))) int ivec4;

#define NT 30
#define DIN 195
#define KPAD 224
#define ASTR 232
#define H1 128
#define H2 64
#define X1STR 136

__device__ __forceinline__ short f2bf(float v) {
    __hip_bfloat16 h = __float2bfloat16(v);
    return __builtin_bit_cast(short, h);
}

__global__ void prep_weights(const float* __restrict__ W1, const float* __restrict__ W2,
                             __hip_bfloat16* __restrict__ W1b, __hip_bfloat16* __restrict__ W2b) {
    int i = blockIdx.x * 256 + threadIdx.x;
    const int n1 = H1 * KPAD;  // 28672
    if (i < n1) {
        int n = i / KPAD, k = i - n * KPAD;
        float v = (k < DIN) ? W1[n * DIN + k] : 0.0f;
        W1b[i] = __float2bfloat16(v);
    } else {
        int j = i - n1;
        if (j < H2 * H1) W2b[j] = __float2bfloat16(W2[j]);
    }
}

template<bool PREP>
__global__ __launch_bounds__(256) void angnet(
    const float* __restrict__ atoms_xyz,
    const float* __restrict__ embed,
    const float* __restrict__ dist_ij,
    const float* __restrict__ b1,
    const float* __restrict__ b2,
    const int* __restrict__ atype,
    const int* __restrict__ aidx,
    const int* __restrict__ ajdx,
    const __hip_bfloat16* __restrict__ W1b,
    const __hip_bfloat16* __restrict__ W2b,
    const float* __restrict__ W1f,
    const float* __restrict__ W2f,
    float* __restrict__ out)
{
    __shared__ __hip_bfloat16 ang[64][ASTR];   // 29696 B, row stride 464B (2-way bank alias: free)
    __shared__ __hip_bfloat16 x1s[64][X1STR];  // 17408 B, row stride 272B (2-way: free)
    __shared__ float est[2][7][64];            // [c][0..5]=e_n, [c][6]=e_i
    __shared__ float rdj[64], rdk[64], fcs[64];
    __shared__ float xyzs[2][6][3];
    __shared__ float dstage[2][6];

    const int tid = threadIdx.x;
    const int c0 = blockIdx.x * 2;

    // ---- Phase 0: zero pad rows (30,31,62,63) and cols 192..231 of all rows ----
    ivec4 zz = {0, 0, 0, 0};
    for (int i = tid; i < 4 * 29; i += 256) {
        int pr = i / 29, c8 = i - pr * 29;
        int row = 30 + (pr & 1) + 32 * (pr >> 1);
        *(ivec4*)&ang[row][c8 * 8] = zz;
    }
    for (int i = tid; i < 64 * 5; i += 256) {
        int row = i / 5, c8 = i - row * 5;
        *(ivec4*)&ang[row][192 + c8 * 8] = zz;
    }

    // ---- Phase A: stage embeddings, xyz, dist ----
    for (int i = tid; i < 2 * 7 * 64; i += 256) {
        int c = i / 448; int rem = i - c * 448;
        int r = rem >> 6, f = rem & 63;
        int ti;
        if (r == 6) ti = atype[aidx[c0 + c]];
        else       ti = atype[ajdx[(c0 + c) * 6 + r]];
        est[c][r][f] = embed[ti * 64 + f];
    }
    if (tid < 36) {
        int c = tid / 18, rr = tid - c * 18;
        int n = rr / 3, ax = rr - n * 3;
        xyzs[c][n][ax] = atoms_xyz[(long)ajdx[(c0 + c) * 6 + n] * 3 + ax];
    }
    {
        int q = tid - 64;
        if (q >= 0 && q < 12) {
            int c = q / 6, n = q - c * 6;
            dstage[c][n] = dist_ij[(c0 + c) * 6 + n];
        }
    }
    __syncthreads();

    // ---- Phase B: per-pair scalars ----
    if (tid < 64) {
        int c = tid >> 5, t = tid & 31;
        int row = tid;
        if (t < NT) {
            int j = t / 5, k2 = t - j * 5;
            int k = k2 + (k2 >= j ? 1 : 0);
            float dij = dstage[c][j], dik = dstage[c][k];
            float dx = xyzs[c][j][0] - xyzs[c][k][0];
            float dy = xyzs[c][j][1] - xyzs[c][k][1];
            float dz = xyzs[c][j][2] - xyzs[c][k][2];
            float djk = sqrtf(dx * dx + dy * dy + dz * dz);
            float mx = fmaxf(dij, dik), mn = fminf(dij, dik);
            float djkn = (djk - mx + mn) / (2.0f * mn);
            rdj[row] = 1.0f / dij;
            rdk[row] = 1.0f / dik;
            ang[row][0] = __float2bfloat16(dij);
            ang[row][1] = __float2bfloat16(dik);
            ang[row][2] = __float2bfloat16(djkn);
            const float PIF = 3.14159265358979323846f;
            float ca = cosf(PIF * fminf(fmaxf(dij * (1.0f / 3.5f), 0.0f), 1.0f));
            float cb = cosf(PIF * fminf(fmaxf(dik * (1.0f / 3.5f), 0.0f), 1.0f));
            fcs[row] = (0.5f * ca + 0.5f) * (0.5f * cb + 0.5f);
        } else {
            rdj[row] = 1.0f; rdk[row] = 1.0f; fcs[row] = 0.0f;
        }
    }
    __syncthreads();

    // ---- Phase C: fill embedding-derived columns ----
    for (int i = tid; i < 2 * NT * 64; i += 256) {
        int c = i / 1920; int rr = i - c * 1920;
        int t = rr >> 6, f = rr & 63;
        int row = c * 32 + t;
        int j = t / 5, k2 = t - j * 5;
        int k = k2 + (k2 >= j ? 1 : 0);
        float ei = est[c][6][f];
        float ej = est[c][j][f] * rdj[row];
        float ek = est[c][k][f] * rdk[row];
        ang[row][3 + f]   = __float2bfloat16(ei);
        ang[row][67 + f]  = __float2bfloat16(ej);
        ang[row][131 + f] = __float2bfloat16(ek);
    }
    __syncthreads();

    // ---- GEMM1: (64 x 224) @ (224 x 128) -> x1s ----
    const int lane = tid & 63;
    const int w = tid >> 6;          // wave id: owns cols [32w, 32w+32)
    const int lrow = lane & 15;
    const int lk = (lane >> 4) * 8;
    const int lr4 = (lane >> 4) * 4;

    facc fz = {0.f, 0.f, 0.f, 0.f};
    facc acc0[4], acc1[4];
    #pragma unroll
    for (int m = 0; m < 4; ++m) { acc0[m] = fz; acc1[m] = fz; }

    #pragma unroll
    for (int k0 = 0; k0 < KPAD / 32; ++k0) {
        bfrag bf0, bf1;
        if (PREP) {
            bf0 = *(const bfrag*)&W1b[(w * 32 + lrow) * KPAD + k0 * 32 + lk];
            bf1 = *(const bfrag*)&W1b[(w * 32 + 16 + lrow) * KPAD + k0 * 32 + lk];
        } else {
            #pragma unroll
            for (int jj = 0; jj < 8; ++jj) {
                int kk = k0 * 32 + lk + jj;
                float v0 = (kk < DIN) ? W1f[(w * 32 + lrow) * DIN + kk] : 0.f;
                float v1 = (kk < DIN) ? W1f[(w * 32 + 16 + lrow) * DIN + kk] : 0.f;
                bf0[jj] = f2bf(v0);
                bf1[jj] = f2bf(v1);
            }
        }
        #pragma unroll
        for (int m = 0; m < 4; ++m) {
            bfrag a = *(const bfrag*)&ang[m * 16 + lrow][k0 * 32 + lk];
            acc0[m] = __builtin_amdgcn_mfma_f32_16x16x32_bf16(a, bf0, acc0[m], 0, 0, 0);
            acc1[m] = __builtin_amdgcn_mfma_f32_16x16x32_bf16(a, bf1, acc1[m], 0, 0, 0);
        }
    }

    // epilogue 1: bias + celu -> x1s (bf16)
    {
        float bias0 = b1[w * 32 + lrow];
        float bias1 = b1[w * 32 + 16 + lrow];
        #pragma unroll
        for (int m = 0; m < 4; ++m) {
            #pragma unroll
            for (int r = 0; r < 4; ++r) {
                int row = m * 16 + lr4 + r;
                float v0 = acc0[m][r] + bias0;
                v0 = v0 > 0.f ? v0 : (__expf(v0) - 1.0f);
                x1s[row][w * 32 + lrow] = __float2bfloat16(v0);
                float v1 = acc1[m][r] + bias1;
                v1 = v1 > 0.f ? v1 : (__expf(v1) - 1.0f);
                x1s[row][w * 32 + 16 + lrow] = __float2bfloat16(v1);
            }
        }
    }
    __syncthreads();

    // ---- GEMM2: (64 x 128) @ (128 x 64), wave w owns cols [16w, 16w+16) ----
    facc acc2[4];
    #pragma unroll
    for (int m = 0; m < 4; ++m) acc2[m] = fz;

    #pragma unroll
    for (int k0 = 0; k0 < 4; ++k0) {
        bfrag b;
        if (PREP) {
            b = *(const bfrag*)&W2b[(w * 16 + lrow) * H1 + k0 * 32 + lk];
        } else {
            #pragma unroll
            for (int jj = 0; jj < 8; ++jj)
                b[jj] = f2bf(W2f[(w * 16 + lrow) * H1 + k0 * 32 + lk + jj]);
        }
        #pragma unroll
        for (int m = 0; m < 4; ++m) {
            bfrag a = *(const bfrag*)&x1s[m * 16 + lrow][k0 * 32 + lk];
            acc2[m] = __builtin_amdgcn_mfma_f32_16x16x32_bf16(a, b, acc2[m], 0, 0, 0);
        }
    }

    // epilogue 2: bias + celu + fc weight + reduce over rows per center
    float bias2 = b2[w * 16 + lrow];
    float p0 = 0.f, p1 = 0.f;
    #pragma unroll
    for (int m = 0; m < 4; ++m) {
        #pragma unroll
        for (int r = 0; r < 4; ++r) {
            int row = m * 16 + lr4 + r;
            float v = acc2[m][r] + bias2;
            v = v > 0.f ? v : (__expf(v) - 1.0f);
            v *= fcs[row];
            if (m < 2) p0 += v; else p1 += v;
        }
    }
    p0 += __shfl_xor(p0, 16);
    p0 += __shfl_xor(p0, 32);
    p1 += __shfl_xor(p1, 16);
    p1 += __shfl_xor(p1, 32);
    if (lane < 16) {
        out[(long)c0 * 64 + w * 16 + lane] = p0;
    } else if (lane < 32) {
        out[(long)(c0 + 1) * 64 + w * 16 + lrow] = p1;
    }
}

extern "C" void kernel_launch(void* const* d_in, const int* in_sizes, int n_in,
                              void* d_out, int out_size, void* d_ws, size_t ws_size,
                              hipStream_t stream) {
    const float* atoms_xyz = (const float*)d_in[0];
    const float* embed     = (const float*)d_in[1];
    const float* dist_ij   = (const float*)d_in[2];
    const float* W1        = (const float*)d_in[3];
    const float* b1        = (const float*)d_in[4];
    const float* W2        = (const float*)d_in[5];
    const float* b2        = (const float*)d_in[6];
    const int*   atype     = (const int*)d_in[7];
    const int*   aidx      = (const int*)d_in[8];
    const int*   ajdx      = (const int*)d_in[9];
    float* out = (float*)d_out;

    const int n_center = in_sizes[8];        // 40000
    const int n_blocks = n_center / 2;       // 2 centers per block

    size_t need = (size_t)(H1 * KPAD + H2 * H1) * sizeof(__hip_bfloat16);
    if (ws_size >= need) {
        __hip_bfloat16* W1b = (__hip_bfloat16*)d_ws;
        __hip_bfloat16* W2b = W1b + H1 * KPAD;
        int prep_total = H1 * KPAD + H2 * H1;
        prep_weights<<<(prep_total + 255) / 256, 256, 0, stream>>>(W1, W2, W1b, W2b);
        angnet<true><<<n_blocks, 256, 0, stream>>>(atoms_xyz, embed, dist_ij, b1, b2,
                                                   atype, aidx, ajdx, W1b, W2b, W1, W2, out);
    } else {
        angnet<false><<<n_blocks, 256, 0, stream>>>(atoms_xyz, embed, dist_ij, b1, b2,
                                                    atype, aidx, ajdx, nullptr, nullptr, W1, W2, out);
    }
}

// Round 2
// 142.576 us; speedup vs baseline: 1.7973x; 1.7973x over previous
//
#include <hip/hip_runtime.h>
#include <hip/hip_bf16.h>

typedef __attribute__((ext_vector_type(8))) short bfrag;
typedef __attribute__((ext_vector_type(4))) float facc;
typedef __attribute__((ext_vector_type(4))) int ivec4;
typedef __attribute__((ext_vector_type(4))) short svec4;

#define DIN 195
#define H1 128
#define H2 64
#define CPB 4
#define ROWS 128
#define TPB 512
#define X1STR 136
#define TLSTR 40
#define VSTR 72

#define W1T_ELEMS (8*7*64*8)   // [mtile][k0][lane][8]
#define W2T_ELEMS (4*4*64*8)   // [mtile][k0][lane][8]

__device__ __forceinline__ short f2bf(float v) {
    __hip_bfloat16 h = __float2bfloat16(v);
    return __builtin_bit_cast(short, h);
}

// Pre-swizzle weights into MFMA A-fragment order (coalesced b128 reads).
// W1 column permutation: new k' < 192 -> orig 3+k' (ei|ej|ek), 192..194 -> orig 0..2 (dij,dik,djkn), >=195 -> 0.
__global__ void prep_weights(const float* __restrict__ W1, const float* __restrict__ W2,
                             __hip_bfloat16* __restrict__ W1t, __hip_bfloat16* __restrict__ W2t) {
    int i = blockIdx.x * 256 + threadIdx.x;
    if (i < W1T_ELEMS) {
        int e = i & 7, l = (i >> 3) & 63;
        int k0 = (i >> 9) % 7, mt = (i >> 9) / 7;
        int h = mt * 16 + (l & 15);
        int kp = k0 * 32 + ((l >> 4) & 3) * 8 + e;
        float v = 0.f;
        if (kp < 192)      v = W1[h * DIN + 3 + kp];
        else if (kp < 195) v = W1[h * DIN + (kp - 192)];
        W1t[i] = __float2bfloat16(v);
    } else {
        int j = i - W1T_ELEMS;
        if (j < W2T_ELEMS) {
            int e = j & 7, l = (j >> 3) & 63;
            int k0 = (j >> 9) & 3, mm = j >> 11;
            int h = mm * 16 + (l & 15);
            int k = k0 * 32 + ((l >> 4) & 3) * 8 + e;
            W2t[j] = __float2bfloat16(W2[h * H1 + k]);
        }
    }
}

template<bool PREP>
__global__ __launch_bounds__(TPB, 4) void angnet(
    const float* __restrict__ atoms_xyz,
    const float* __restrict__ embed,
    const float* __restrict__ dist_ij,
    const float* __restrict__ b1,
    const float* __restrict__ b2,
    const int* __restrict__ atype,
    const int* __restrict__ aidx,
    const int* __restrict__ ajdx,
    const __hip_bfloat16* __restrict__ W1t,
    const __hip_bfloat16* __restrict__ W2t,
    const float* __restrict__ W1f,
    const float* __restrict__ W2f,
    float* __restrict__ out)
{
    __shared__ __align__(16) __hip_bfloat16 x1s[ROWS][X1STR];   // 34816 B
    __shared__ __align__(16) __hip_bfloat16 tail[ROWS][TLSTR];  // 10240 B
    __shared__ __align__(16) __hip_bfloat16 vst[CPB][7][VSTR];  //  4032 B
    __shared__ float fcs[ROWS];
    __shared__ float dstage[CPB][6];
    __shared__ float xyzs[CPB][6][3];
    __shared__ int   tidx[CPB][7];

    const int tid = threadIdx.x;
    const int C0 = blockIdx.x * CPB;

    // ---- Phase 1: zero tail, stage indices / dist / xyz ----
    {
        ivec4 zz = {0, 0, 0, 0};
        for (int i = tid; i < ROWS * TLSTR / 8; i += TPB)
            ((ivec4*)tail)[i] = zz;
    }
    if (tid < CPB * 7) {
        int c = tid / 7, r = tid % 7;
        tidx[c][r] = (r == 6) ? atype[aidx[C0 + c]] : atype[ajdx[(C0 + c) * 6 + r]];
    } else if (tid < CPB * 7 + CPB * 18) {
        int q = tid - CPB * 7; int c = q / 18, rr = q % 18; int n = rr / 3, ax = rr % 3;
        xyzs[c][n][ax] = atoms_xyz[(long)ajdx[(C0 + c) * 6 + n] * 3 + ax];
    } else if (tid < CPB * 7 + CPB * 18 + CPB * 6) {
        int q = tid - CPB * 7 - CPB * 18; int c = q / 6, n = q % 6;
        dstage[c][n] = dist_ij[(C0 + c) * 6 + n];
    }
    __syncthreads();

    // ---- Phase 2: build vstage (7 distinct 64-vectors per center) + per-row scalars ----
    if (tid < CPB * 7 * 8) {                     // 224 tasks: 8 bf16 each
        int c = tid / 56, rem = tid % 56, v = rem / 8, ch = rem % 8;
        int ti = tidx[c][v];
        float sc = (v < 6) ? (1.0f / dstage[c][v]) : 1.0f;
        const float* ep = &embed[ti * 64 + ch * 8];
        float4 e0 = *(const float4*)ep;
        float4 e1 = *(const float4*)(ep + 4);
        bfrag t;
        t[0] = f2bf(e0.x * sc); t[1] = f2bf(e0.y * sc);
        t[2] = f2bf(e0.z * sc); t[3] = f2bf(e0.w * sc);
        t[4] = f2bf(e1.x * sc); t[5] = f2bf(e1.y * sc);
        t[6] = f2bf(e1.z * sc); t[7] = f2bf(e1.w * sc);
        *(bfrag*)&vst[c][v][ch * 8] = t;
    } else if (tid >= 256 && tid < 256 + CPB * 30) {
        int q = tid - 256; int c = q / 30, t = q % 30;
        int j = t / 5, k2 = t - j * 5, k = k2 + (k2 >= j ? 1 : 0);
        float dij = dstage[c][j], dik = dstage[c][k];
        float dx = xyzs[c][j][0] - xyzs[c][k][0];
        float dy = xyzs[c][j][1] - xyzs[c][k][1];
        float dz = xyzs[c][j][2] - xyzs[c][k][2];
        float djk = sqrtf(dx * dx + dy * dy + dz * dz);
        float mx = fmaxf(dij, dik), mn = fminf(dij, dik);
        float djkn = (djk - mx + mn) / (2.0f * mn);
        int r = c * 32 + t;
        tail[r][0] = __float2bfloat16(dij);
        tail[r][1] = __float2bfloat16(dik);
        tail[r][2] = __float2bfloat16(djkn);
        const float PIF = 3.14159265358979323846f;
        float ca = __cosf(PIF * (dij * (1.0f / 3.5f)));
        float cb = __cosf(PIF * (dik * (1.0f / 3.5f)));
        fcs[r] = (0.5f * ca + 0.5f) * (0.5f * cb + 0.5f);
    } else if (tid >= 376 && tid < 384) {
        int p = tid - 376;
        fcs[(p >> 1) * 32 + 30 + (p & 1)] = 0.f;
    }
    __syncthreads();

    const int w = tid >> 6, l = tid & 63, lr = l & 15, lq = l >> 4;

    // ---- GEMM1: D1[h][r] = sum_k W1[h][k] * ang[r][k]; wave w owns h in [16w,16w+16), all 128 r ----
    int jn[8], kn[8];
    #pragma unroll
    for (int n = 0; n < 8; ++n) {
        int t = (n & 1) * 16 + lr;
        int j = t / 5, k2 = t - j * 5, k = k2 + (k2 >= j ? 1 : 0);
        if (t >= 30) { j = 0; k = 0; }
        jn[n] = j; kn[n] = k;
    }
    facc a1[8];
    #pragma unroll
    for (int n = 0; n < 8; ++n) a1[n] = (facc){0.f, 0.f, 0.f, 0.f};

    #pragma unroll
    for (int k0 = 0; k0 < 7; ++k0) {
        bfrag Af;
        if (PREP) {
            Af = *(const bfrag*)&W1t[(w * 7 + k0) * 512 + l * 8];
        } else {
            #pragma unroll
            for (int e = 0; e < 8; ++e) {
                int kp = k0 * 32 + lq * 8 + e;
                int h = w * 16 + lr;
                float v = 0.f;
                if (kp < 192)      v = W1f[h * DIN + 3 + kp];
                else if (kp < 195) v = W1f[h * DIN + kp - 192];
                Af[e] = f2bf(v);
            }
        }
        #pragma unroll
        for (int n = 0; n < 8; ++n) {
            const __hip_bfloat16* bp;
            if (k0 < 2)      bp = &vst[n >> 1][6][(k0 & 1) * 32 + lq * 8];
            else if (k0 < 4) bp = &vst[n >> 1][jn[n]][(k0 & 1) * 32 + lq * 8];
            else if (k0 < 6) bp = &vst[n >> 1][kn[n]][(k0 & 1) * 32 + lq * 8];
            else             bp = &tail[n * 16 + lr][lq * 8];
            bfrag Bf = *(const bfrag*)bp;
            a1[n] = __builtin_amdgcn_mfma_f32_16x16x32_bf16(Af, Bf, a1[n], 0, 0, 0);
        }
    }

    // ---- Epilogue 1: bias + celu -> x1s (b64 writes, 4 consecutive h) ----
    {
        float b1v[4];
        #pragma unroll
        for (int g = 0; g < 4; ++g) b1v[g] = b1[w * 16 + lq * 4 + g];
        #pragma unroll
        for (int n = 0; n < 8; ++n) {
            svec4 pk;
            #pragma unroll
            for (int g = 0; g < 4; ++g) {
                float v = a1[n][g] + b1v[g];
                v = v > 0.f ? v : (__expf(v) - 1.f);
                pk[g] = f2bf(v);
            }
            *(svec4*)&x1s[n * 16 + lr][w * 16 + lq * 4] = pk;
        }
    }
    __syncthreads();

    // ---- GEMM2: D2[o][r] = sum_k W2[o][k] * x1[r][k]; wave (q=w>>2, mm=w&3): o-tile mm, n-tiles 4q..4q+3 ----
    const int mm = w & 3, q = w >> 2;
    facc a2[4];
    #pragma unroll
    for (int i = 0; i < 4; ++i) a2[i] = (facc){0.f, 0.f, 0.f, 0.f};

    #pragma unroll
    for (int k0 = 0; k0 < 4; ++k0) {
        bfrag Af;
        if (PREP) {
            Af = *(const bfrag*)&W2t[(mm * 4 + k0) * 512 + l * 8];
        } else {
            #pragma unroll
            for (int e = 0; e < 8; ++e)
                Af[e] = f2bf(W2f[(mm * 16 + lr) * H1 + k0 * 32 + lq * 8 + e]);
        }
        #pragma unroll
        for (int i = 0; i < 4; ++i) {
            bfrag Bf = *(const bfrag*)&x1s[(q * 4 + i) * 16 + lr][k0 * 32 + lq * 8];
            a2[i] = __builtin_amdgcn_mfma_f32_16x16x32_bf16(Af, Bf, a2[i], 0, 0, 0);
        }
    }

    // ---- Epilogue 2: bias + celu + fc, 16-lane reduce over r, direct global store ----
    {
        float b2v[4];
        #pragma unroll
        for (int g = 0; g < 4; ++g) b2v[g] = b2[mm * 16 + lq * 4 + g];
        float s[4][4];
        #pragma unroll
        for (int i = 0; i < 4; ++i) {
            float fr = fcs[(q * 4 + i) * 16 + lr];
            #pragma unroll
            for (int g = 0; g < 4; ++g) {
                float v = a2[i][g] + b2v[g];
                v = v > 0.f ? v : (__expf(v) - 1.f);
                s[i][g] = v * fr;
            }
        }
        #pragma unroll
        for (int st = 1; st < 16; st <<= 1) {
            #pragma unroll
            for (int i = 0; i < 4; ++i)
                #pragma unroll
                for (int g = 0; g < 4; ++g)
                    s[i][g] += __shfl_xor(s[i][g], st);
        }
        if (lr == 0) {
            #pragma unroll
            for (int u = 0; u < 2; ++u)
                #pragma unroll
                for (int g = 0; g < 4; ++g)
                    out[(long)(C0 + q * 2 + u) * 64 + mm * 16 + lq * 4 + g] = s[2 * u][g] + s[2 * u + 1][g];
        }
    }
}

extern "C" void kernel_launch(void* const* d_in, const int* in_sizes, int n_in,
                              void* d_out, int out_size, void* d_ws, size_t ws_size,
                              hipStream_t stream) {
    const float* atoms_xyz = (const float*)d_in[0];
    const float* embed     = (const float*)d_in[1];
    const float* dist_ij   = (const float*)d_in[2];
    const float* W1        = (const float*)d_in[3];
    const float* b1        = (const float*)d_in[4];
    const float* W2        = (const float*)d_in[5];
    const float* b2        = (const float*)d_in[6];
    const int*   atype     = (const int*)d_in[7];
    const int*   aidx      = (const int*)d_in[8];
    const int*   ajdx      = (const int*)d_in[9];
    float* out = (float*)d_out;

    const int n_center = in_sizes[8];            // 40000
    const int n_blocks = n_center / CPB;         // 10000

    size_t need = (size_t)(W1T_ELEMS + W2T_ELEMS) * sizeof(__hip_bfloat16);
    if (ws_size >= need) {
        __hip_bfloat16* W1t = (__hip_bfloat16*)d_ws;
        __hip_bfloat16* W2t = W1t + W1T_ELEMS;
        int prep_total = W1T_ELEMS + W2T_ELEMS;
        prep_weights<<<(prep_total + 255) / 256, 256, 0, stream>>>(W1, W2, W1t, W2t);
        angnet<true><<<n_blocks, TPB, 0, stream>>>(atoms_xyz, embed, dist_ij, b1, b2,
                                                   atype, aidx, ajdx, W1t, W2t, W1, W2, out);
    } else {
        angnet<false><<<n_blocks, TPB, 0, stream>>>(atoms_xyz, embed, dist_ij, b1, b2,
                                                    atype, aidx, ajdx, nullptr, nullptr, W1, W2, out);
    }
}

// Round 4
// 119.187 us; speedup vs baseline: 2.1501x; 1.1962x over previous
//
#include <hip/hip_runtime.h>
#include <hip/hip_bf16.h>

typedef __attribute__((ext_vector_type(8))) short bfrag;
typedef __attribute__((ext_vector_type(4))) float facc;
typedef __attribute__((ext_vector_type(4))) int ivec4;
typedef __attribute__((ext_vector_type(2))) int ivec2;
typedef __attribute__((ext_vector_type(4))) short svec4;

#define DIN 195
#define H1 128
#define H2 64
#define CPB 4
#define ROWS 128
#define TPB 512
#define X1STR 136
#define VSTR 72

#define W1T_ELEMS (8*7*64*8)   // [mtile][k0][lane][8]
#define W2T_ELEMS (4*4*64*8)   // [ntile][k0][lane][8]

__device__ __forceinline__ short f2bf(float v) {
    __hip_bfloat16 h = __float2bfloat16(v);
    return __builtin_bit_cast(short, h);
}
__device__ __forceinline__ float celu1(float v) {
    return v > 0.f ? v : (__expf(v) - 1.f);
}

// W1t: A-fragment order. Column permutation: kp<192 -> orig 3+kp (ei|ej|ek),
// kp 192..194 -> orig 0..2 (dij,dik,djkn), kp==195 -> b1 (bias column), else 0.
__global__ void prep_weights(const float* __restrict__ W1, const float* __restrict__ W2,
                             const float* __restrict__ b1,
                             __hip_bfloat16* __restrict__ W1t, __hip_bfloat16* __restrict__ W2t) {
    int i = blockIdx.x * 256 + threadIdx.x;
    if (i < W1T_ELEMS) {
        int e = i & 7, l = (i >> 3) & 63;
        int k0 = (i >> 9) % 7, mt = (i >> 9) / 7;
        int h = mt * 16 + (l & 15);
        int kp = k0 * 32 + ((l >> 4) & 3) * 8 + e;
        float v = 0.f;
        if (kp < 192)       v = W1[h * DIN + 3 + kp];
        else if (kp < 195)  v = W1[h * DIN + (kp - 192)];
        else if (kp == 195) v = b1[h];
        W1t[i] = __float2bfloat16(v);
    } else {
        int j = i - W1T_ELEMS;
        if (j < W2T_ELEMS) {
            int e = j & 7, l = (j >> 3) & 63;
            int k0 = (j >> 9) & 3, nt = j >> 11;
            int h = nt * 16 + (l & 15);
            int k = k0 * 32 + ((l >> 4) & 3) * 8 + e;
            W2t[j] = __float2bfloat16(W2[h * H1 + k]);
        }
    }
}

template<bool PREP>
__global__ __launch_bounds__(TPB, 8) void angnet(
    const float* __restrict__ atoms_xyz,
    const float* __restrict__ embed,
    const float* __restrict__ dist_ij,
    const float* __restrict__ b1,
    const float* __restrict__ b2,
    const int* __restrict__ atype,
    const int* __restrict__ aidx,
    const int* __restrict__ ajdx,
    const __hip_bfloat16* __restrict__ W1t,
    const __hip_bfloat16* __restrict__ W2t,
    const float* __restrict__ W1f,
    const float* __restrict__ W2f,
    float* __restrict__ out)
{
    __shared__ __align__(16) __hip_bfloat16 x1s[ROWS][X1STR];     // 34816 B (staging aliased at start)
    __shared__ __align__(16) __hip_bfloat16 vst[CPB][7][VSTR];    //  4032 B
    __shared__ __align__(16) __hip_bfloat16 tvp[512];             //  1024 B: tailv[128][4] then partials[8][64]
    __shared__ __hip_bfloat16 fcs[ROWS];                          //   256 B

    // staging aliased into x1s (dead once epilogue-1 writes x1s)
    float* stg  = (float*)&x1s[0][0];      // [0..71] xyzs(c,n,ax)=stg[c*18+n*3+ax]; [72..95] dstage(c,n)=stg[72+c*6+n]
    int*   tidxp = (int*)(stg + 96);       // [0..27] tidx(c,r)

    const int tid = threadIdx.x;
    const int C0 = blockIdx.x * CPB;

    // ---- Phase 1: zero tailv, stage indices / xyz / dist ----
    if (tid < 64) {
        ivec4 zz = {0, 0, 0, 0};
        ((ivec4*)tvp)[tid] = zz;
    } else if (tid >= 64 && tid < 92) {
        int q = tid - 64, c = q / 7, r = q % 7;
        tidxp[c * 7 + r] = (r == 6) ? atype[aidx[C0 + c]] : atype[ajdx[(C0 + c) * 6 + r]];
    } else if (tid >= 96 && tid < 168) {
        int q = tid - 96, c = q / 18, rr = q % 18, n = rr / 3, ax = rr % 3;
        stg[c * 18 + n * 3 + ax] = atoms_xyz[(long)ajdx[(C0 + c) * 6 + n] * 3 + ax];
    } else if (tid >= 168 && tid < 192) {
        int q = tid - 168, c = q / 6, n = q % 6;
        stg[72 + c * 6 + n] = dist_ij[(C0 + c) * 6 + n];
    }
    __syncthreads();

    // ---- Phase 2: build vst (7 distinct 64-vectors per center) + per-row scalars ----
    if (tid < CPB * 7 * 8) {
        int c = tid / 56, rem = tid % 56, v = rem / 8, ch = rem % 8;
        int ti = tidxp[c * 7 + v];
        float sc = (v < 6) ? (1.0f / stg[72 + c * 6 + v]) : 1.0f;
        const float* ep = &embed[ti * 64 + ch * 8];
        float4 e0 = *(const float4*)ep;
        float4 e1 = *(const float4*)(ep + 4);
        bfrag t;
        t[0] = f2bf(e0.x * sc); t[1] = f2bf(e0.y * sc);
        t[2] = f2bf(e0.z * sc); t[3] = f2bf(e0.w * sc);
        t[4] = f2bf(e1.x * sc); t[5] = f2bf(e1.y * sc);
        t[6] = f2bf(e1.z * sc); t[7] = f2bf(e1.w * sc);
        *(bfrag*)&vst[c][v][ch * 8] = t;
    } else if (tid >= 256 && tid < 256 + CPB * 30) {
        int q = tid - 256, c = q / 30, t = q % 30;
        int j = t / 5, k2 = t - j * 5, k = k2 + (k2 >= j ? 1 : 0);
        float dij = stg[72 + c * 6 + j], dik = stg[72 + c * 6 + k];
        float dx = stg[c * 18 + j * 3 + 0] - stg[c * 18 + k * 3 + 0];
        float dy = stg[c * 18 + j * 3 + 1] - stg[c * 18 + k * 3 + 1];
        float dz = stg[c * 18 + j * 3 + 2] - stg[c * 18 + k * 3 + 2];
        float djk = sqrtf(dx * dx + dy * dy + dz * dz);
        float mx = fmaxf(dij, dik), mn = fminf(dij, dik);
        float djkn = (djk - mx + mn) / (2.0f * mn);
        int r = c * 32 + t;
        svec4 pk;
        pk[0] = f2bf(dij); pk[1] = f2bf(dik); pk[2] = f2bf(djkn); pk[3] = f2bf(1.0f);
        *(svec4*)&tvp[r * 4] = pk;
        const float PIF = 3.14159265358979323846f;
        float ca = __cosf(PIF * (dij * (1.0f / 3.5f)));
        float cb = __cosf(PIF * (dik * (1.0f / 3.5f)));
        fcs[r] = __float2bfloat16((0.5f * ca + 0.5f) * (0.5f * cb + 0.5f));
    } else if (tid >= 376 && tid < 384) {
        int p = tid - 376;
        fcs[(p >> 1) * 32 + 30 + (p & 1)] = __float2bfloat16(0.f);
    }
    __syncthreads();

    const int w = tid >> 6, l = tid & 63, lr = l & 15, lq = l >> 4;

    // ---- GEMM1: D1[h][r], wave w owns h in [16w,16w+16), all 128 r ----
    // per-thread loop-invariant B addressing
    int jA = lr / 5, k2A = lr % 5; int kA = k2A + (k2A >= jA ? 1 : 0);
    int tB = 16 + lr, jB = 0, kB = 0;
    if (tB < 30) { jB = tB / 5; int k2B = tB % 5; kB = k2B + (k2B >= jB ? 1 : 0); }
    const int joA = jA * VSTR, joB = jB * VSTR, koA = kA * VSTR, koB = kB * VSTR;
    const __hip_bfloat16* vb[4];
    #pragma unroll
    for (int c = 0; c < 4; ++c) vb[c] = &vst[c][0][lq * 8];

    facc a1[8];
    #pragma unroll
    for (int n = 0; n < 8; ++n) a1[n] = (facc){0.f, 0.f, 0.f, 0.f};

    #pragma unroll
    for (int k0 = 0; k0 < 7; ++k0) {
        bfrag Af;
        if (PREP) {
            Af = *(const bfrag*)&W1t[(w * 7 + k0) * 512 + l * 8];
        } else {
            #pragma unroll
            for (int e = 0; e < 8; ++e) {
                int kp = k0 * 32 + lq * 8 + e;
                int h = w * 16 + lr;
                float v = 0.f;
                if (kp < 192)       v = W1f[h * DIN + 3 + kp];
                else if (kp < 195)  v = W1f[h * DIN + kp - 192];
                else if (kp == 195) v = b1[h];
                Af[e] = f2bf(v);
            }
        }
        #pragma unroll
        for (int n = 0; n < 8; ++n) {
            bfrag Bf;
            if (k0 < 6) {
                const __hip_bfloat16* bp;
                if (k0 < 2)      bp = vb[n >> 1] + 6 * VSTR + (k0 & 1) * 32;
                else if (k0 < 4) bp = vb[n >> 1] + ((n & 1) ? joB : joA) + (k0 & 1) * 32;
                else             bp = vb[n >> 1] + ((n & 1) ? koB : koA) + (k0 & 1) * 32;
                Bf = *(const bfrag*)bp;
            } else {
                // tail tile: only lq==0 lanes carry data (kp 192..199), rest zero
                svec4 tv = *(const svec4*)&tvp[(n * 16 + lr) * 4];
                ivec2 ti = __builtin_bit_cast(ivec2, tv);
                int lo = (lq == 0) ? ti[0] : 0;
                int hi = (lq == 0) ? ti[1] : 0;
                ivec4 bi = {lo, hi, 0, 0};
                Bf = __builtin_bit_cast(bfrag, bi);
            }
            a1[n] = __builtin_amdgcn_mfma_f32_16x16x32_bf16(Af, Bf, a1[n], 0, 0, 0);
        }
    }

    // ---- Epilogue 1: celu -> x1s (bias folded into GEMM1) ----
    #pragma unroll
    for (int n = 0; n < 8; ++n) {
        svec4 pk;
        #pragma unroll
        for (int g = 0; g < 4; ++g) pk[g] = f2bf(celu1(a1[n][g]));
        *(svec4*)&x1s[n * 16 + lr][w * 16 + lq * 4] = pk;
    }
    __syncthreads();

    // ---- GEMM2: D2[r][o]; wave w owns rows [16w,16w+16), all 64 o ----
    facc a2[4];
    #pragma unroll
    for (int n = 0; n < 4; ++n) a2[n] = (facc){0.f, 0.f, 0.f, 0.f};

    #pragma unroll
    for (int k0 = 0; k0 < 4; ++k0) {
        bfrag Af2 = *(const bfrag*)&x1s[w * 16 + lr][k0 * 32 + lq * 8];
        #pragma unroll
        for (int n = 0; n < 4; ++n) {
            bfrag Bf2;
            if (PREP) {
                Bf2 = *(const bfrag*)&W2t[(n * 4 + k0) * 512 + l * 8];
            } else {
                #pragma unroll
                for (int e = 0; e < 8; ++e)
                    Bf2[e] = f2bf(W2f[(n * 16 + lr) * H1 + k0 * 32 + lq * 8 + e]);
            }
            a2[n] = __builtin_amdgcn_mfma_f32_16x16x32_bf16(Af2, Bf2, a2[n], 0, 0, 0);
        }
    }

    // ---- Epilogue 2: celu + fc, g-sum + 2 shfls, bf16 partials ----
    {
        float fr[4];
        #pragma unroll
        for (int g = 0; g < 4; ++g) fr[g] = __bfloat162float(fcs[w * 16 + lq * 4 + g]);
        float t[4];
        #pragma unroll
        for (int n = 0; n < 4; ++n) {
            float b2v = b2[n * 16 + lr];
            float s = 0.f;
            #pragma unroll
            for (int g = 0; g < 4; ++g)
                s += celu1(a2[n][g] + b2v) * fr[g];
            s += __shfl_xor(s, 16);
            s += __shfl_xor(s, 32);
            t[n] = s;
        }
        if (lq == 0) {
            #pragma unroll
            for (int n = 0; n < 4; ++n)
                tvp[w * 64 + n * 16 + lr] = __float2bfloat16(t[n]);
        }
    }
    __syncthreads();

    // ---- Final: combine the two half-center partials, coalesced store ----
    if (tid < 256) {
        int c = tid >> 6, o = tid & 63;
        out[(long)(C0 + c) * 64 + o] =
            __bfloat162float(tvp[(2 * c) * 64 + o]) + __bfloat162float(tvp[(2 * c + 1) * 64 + o]);
    }
}

extern "C" void kernel_launch(void* const* d_in, const int* in_sizes, int n_in,
                              void* d_out, int out_size, void* d_ws, size_t ws_size,
                              hipStream_t stream) {
    const float* atoms_xyz = (const float*)d_in[0];
    const float* embed     = (const float*)d_in[1];
    const float* dist_ij   = (const float*)d_in[2];
    const float* W1        = (const float*)d_in[3];
    const float* b1        = (const float*)d_in[4];
    const float* W2        = (const float*)d_in[5];
    const float* b2        = (const float*)d_in[6];
    const int*   atype     = (const int*)d_in[7];
    const int*   aidx      = (const int*)d_in[8];
    const int*   ajdx      = (const int*)d_in[9];
    float* out = (float*)d_out;

    const int n_center = in_sizes[8];            // 40000
    const int n_blocks = n_center / CPB;         // 10000

    size_t need = (size_t)(W1T_ELEMS + W2T_ELEMS) * sizeof(__hip_bfloat16);
    if (ws_size >= need) {
        __hip_bfloat16* W1t = (__hip_bfloat16*)d_ws;
        __hip_bfloat16* W2t = W1t + W1T_ELEMS;
        int prep_total = W1T_ELEMS + W2T_ELEMS;
        prep_weights<<<(prep_total + 255) / 256, 256, 0, stream>>>(W1, W2, b1, W1t, W2t);
        angnet<true><<<n_blocks, TPB, 0, stream>>>(atoms_xyz, embed, dist_ij, b1, b2,
                                                   atype, aidx, ajdx, W1t, W2t, W1, W2, out);
    } else {
        angnet<false><<<n_blocks, TPB, 0, stream>>>(atoms_xyz, embed, dist_ij, b1, b2,
                                                    atype, aidx, ajdx, nullptr, nullptr, W1, W2, out);
    }
}